// Round 9
// baseline (204.504 us; speedup 1.0000x reference)
//
#include <hip/hip_runtime.h>
#include <hip/hip_bf16.h>
#include <stdint.h>

#define NROW 10000
#define DIM 128
#define NP 10240          // rows padded to 640 tiles of 16 (divisible by JC=8 chunks)
#define KSEL 15
#define NTILES (NP / 16)  // 640

typedef __attribute__((ext_vector_type(4))) float f32x4;
typedef __attribute__((ext_vector_type(8))) short s16x8;
using bf16_t = __hip_bfloat16;

// ---------------------------------------------------------------- convert
// One wave per row. Writes X in MFMA-fragment-packed layout:
//   elem e = kk*32 + g*8 + pos of row r  ->  ((tile*4+kk)*64 + g*16 + (r&15))*8 + pos
// so an A-fragment load in knn_topk is base + lane*16B (fully coalesced), and
// B-fragments come from the same layout. Also sqh = 1024 - 0.5*|x|^2 (MFMA C-in).
// Pad rows: zero data, sqh = 1.0 -> key ~1.0, never beats real keys (~870+).
__global__ __launch_bounds__(256)
void knn_convert(const float* __restrict__ x0, const float* __restrict__ x1,
                 bf16_t* __restrict__ xp, float* __restrict__ sqh,
                 unsigned* __restrict__ counter)
{
    if (blockIdx.x == 0 && threadIdx.x == 0) *counter = 0u;
    const int rg   = blockIdx.x * 4 + (threadIdx.x >> 6);
    const int lane = threadIdx.x & 63;
    if (rg >= 2 * NP) return;
    const int m = rg >= NP ? 1 : 0;
    const int r = rg - m * NP;
    const float* src = m ? x1 : x0;

    float2 v = make_float2(0.f, 0.f);
    float  s = 0.f;
    if (r < NROW) {
        v = *(const float2*)(src + (size_t)r * DIM + lane * 2);
        s = v.x * v.x + v.y * v.y;
    }
    const uint32_t pk = (uint32_t)__bfloat16_as_ushort(__float2bfloat16(v.x))
                      | ((uint32_t)__bfloat16_as_ushort(__float2bfloat16(v.y)) << 16);
    const int e   = lane * 2;
    const int kk  = e >> 5;
    const int gg  = (e >> 3) & 3;
    const int pos = e & 7;
    const size_t off = ((((size_t)m * NTILES + (r >> 4)) * 4 + kk) * 64
                        + (size_t)(gg * 16 + (r & 15))) * 8 + pos;   // even
    *(uint32_t*)(xp + off) = pk;
    #pragma unroll
    for (int o = 32; o; o >>= 1) s += __shfl_down(s, o);
    if (lane == 0) sqh[m * NP + r] = (r < NROW) ? fmaf(s, -0.5f, 1024.0f) : 1.0f;
}

// ---------------------------------------------------------------- main
// Key = dot(Xj,Xi) + 1024 - 0.5*sq[j] (bias in MFMA C-in), truncated to 22 bits
// with 10-bit chunk-local index in the low bits (monotonic u32). Branchless
// top-15 per lane: 14x v_med3_u32 + 1 umax in 15 named regs. Modulo-2 software
// pipeline: two register sets (even/odd tiles), each slot computes from its set
// then reloads the SAME variables (no rotation moves); uniform prefetch
// pointers stepped on the scalar pipe; 32-bit lane voffset; no tail clamp
// (xp/sqh over-allocated; overrun prefetches are never consumed).
#define INS(k, hi, lo) asm("v_med3_u32 %0, %1, %2, %0" : "+v"(lo) : "v"(k), "v"(hi))

#define INSERT4(acc, idxb)                                                        \
    do {                                                                          \
        _Pragma("unroll")                                                         \
        for (int r_ = 0; r_ < 4; ++r_) {                                          \
            const uint32_t b_ = __float_as_uint((acc)[r_]);                       \
            const uint32_t k_ = (b_ & 0xFFFFFC00u) | ((idxb) | (uint32_t)r_);     \
            INS(k_, q13, q14); INS(k_, q12, q13); INS(k_, q11, q12);              \
            INS(k_, q10, q11); INS(k_, q9,  q10); INS(k_, q8,  q9);               \
            INS(k_, q7,  q8);  INS(k_, q6,  q7);  INS(k_, q5,  q6);               \
            INS(k_, q4,  q5);  INS(k_, q3,  q4);  INS(k_, q2,  q3);               \
            INS(k_, q1,  q2);  INS(k_, q0,  q1);                                  \
            q0 = (q0 > k_) ? q0 : k_;                                             \
        }                                                                         \
    } while (0)

template<int JC>
__global__ __launch_bounds__(256, 4)
void knn_topk(const bf16_t* __restrict__ xp, const float* __restrict__ sqh,
              uint32_t* __restrict__ pkey, uint16_t* __restrict__ pidx)
{
    __shared__ uint32_t lv[4][64][KSEL];   // keys only; j reconstructed from key bits

    const int m     = blockIdx.z;
    const int chunk = blockIdx.y;
    const int ib    = blockIdx.x * 64;
    const int wave  = threadIdx.x >> 6;
    const int lane  = threadIdx.x & 63;
    const int li    = lane & 15;
    const int g     = lane >> 4;

    const bf16_t* XP = xp + (size_t)m * NP * DIM;
    const float*  SQ = sqh + m * NP;

    const int i  = ib + wave * 16 + li;
    const int ti = (ib >> 4) + wave;       // i-tile index for B-fragments

    // B fragments from packed layout: lane holds B[k=kk*32+g*8+e][col=li] = X[i][k]
    s16x8 bfr[4];
    #pragma unroll
    for (int kk = 0; kk < 4; ++kk)
        bfr[kk] = *(const s16x8*)(XP + (((size_t)ti * 4 + kk) * 64 + (size_t)(g * 16 + li)) * 8);

    uint32_t q0 = 0, q1 = 0, q2 = 0, q3 = 0, q4 = 0, q5 = 0, q6 = 0, q7 = 0,
             q8 = 0, q9 = 0, q10 = 0, q11 = 0, q12 = 0, q13 = 0, q14 = 0;

    const int TPC = NTILES / JC;           // tiles per chunk (80 at JC=8, even)
    const int t0  = chunk * TPC;

    const bf16_t* XC = XP + (size_t)t0 * 2048;   // chunk base (uniform)
    const float*  SC = SQ + t0 * 16;             // chunk sq base (uniform)
    const int     la = lane * 8;                 // lane A-frag offset (elements, 16B)
    const int     sg = g * 4;                    // lane sq offset

    // Preload tiles 0 (set A) and 1 (set B); sq issued first (oldest -> counted waits).
    f32x4 sA = *(const f32x4*)(SC + sg);
    s16x8 a0 = *(const s16x8*)(XC + la);
    s16x8 a1 = *(const s16x8*)(XC + la + 512);
    s16x8 a2 = *(const s16x8*)(XC + la + 1024);
    s16x8 a3 = *(const s16x8*)(XC + la + 1536);
    f32x4 sB = *(const f32x4*)(SC + sg + 16);
    s16x8 c0 = *(const s16x8*)(XC + la + 2048);
    s16x8 c1 = *(const s16x8*)(XC + la + 2048 + 512);
    s16x8 c2 = *(const s16x8*)(XC + la + 2048 + 1024);
    s16x8 c3 = *(const s16x8*)(XC + la + 2048 + 1536);

    const bf16_t* pfA = XC + 2 * 2048;   // uniform prefetch base, set A (tile 2p+2)
    const bf16_t* pfB = XC + 3 * 2048;   // set B (tile 2p+3)
    const float*  sfA = SC + 2 * 16;
    const float*  sfB = SC + 3 * 16;

    for (int p = 0; p < TPC / 2; ++p) {
        // ---- slot A: compute tile 2p from set A, then reload set A with tile 2p+2
        {
            f32x4 acc = __builtin_amdgcn_mfma_f32_16x16x32_bf16(a0, bfr[0], sA, 0, 0, 0);
            acc = __builtin_amdgcn_mfma_f32_16x16x32_bf16(a1, bfr[1], acc, 0, 0, 0);
            acc = __builtin_amdgcn_mfma_f32_16x16x32_bf16(a2, bfr[2], acc, 0, 0, 0);
            acc = __builtin_amdgcn_mfma_f32_16x16x32_bf16(a3, bfr[3], acc, 0, 0, 0);
            sA = *(const f32x4*)(sfA + sg);          sfA += 32;
            a0 = *(const s16x8*)(pfA + la);
            a1 = *(const s16x8*)(pfA + la + 512);
            a2 = *(const s16x8*)(pfA + la + 1024);
            a3 = *(const s16x8*)(pfA + la + 1536);   pfA += 4096;
            INSERT4(acc, (uint32_t)(p << 3));
        }
        // ---- slot B: compute tile 2p+1 from set B, then reload set B with tile 2p+3
        {
            f32x4 acc = __builtin_amdgcn_mfma_f32_16x16x32_bf16(c0, bfr[0], sB, 0, 0, 0);
            acc = __builtin_amdgcn_mfma_f32_16x16x32_bf16(c1, bfr[1], acc, 0, 0, 0);
            acc = __builtin_amdgcn_mfma_f32_16x16x32_bf16(c2, bfr[2], acc, 0, 0, 0);
            acc = __builtin_amdgcn_mfma_f32_16x16x32_bf16(c3, bfr[3], acc, 0, 0, 0);
            sB = *(const f32x4*)(sfB + sg);          sfB += 32;
            c0 = *(const s16x8*)(pfB + la);
            c1 = *(const s16x8*)(pfB + la + 512);
            c2 = *(const s16x8*)(pfB + la + 1024);
            c3 = *(const s16x8*)(pfB + la + 1536);   pfB += 4096;
            INSERT4(acc, (uint32_t)(p << 3) | 4u);
        }
    }

    lv[wave][lane][0]  = q0;  lv[wave][lane][1]  = q1;  lv[wave][lane][2]  = q2;
    lv[wave][lane][3]  = q3;  lv[wave][lane][4]  = q4;  lv[wave][lane][5]  = q5;
    lv[wave][lane][6]  = q6;  lv[wave][lane][7]  = q7;  lv[wave][lane][8]  = q8;
    lv[wave][lane][9]  = q9;  lv[wave][lane][10] = q10; lv[wave][lane][11] = q11;
    lv[wave][lane][12] = q12; lv[wave][lane][13] = q13; lv[wave][lane][14] = q14;
    __syncthreads();

    // 4-way merge of the lane-group lists for this i; write sorted 15.
    if (g == 0 && i < NROW) {
        int p0 = 0, p1 = 0, p2 = 0, p3 = 0;
        uint32_t v0 = lv[wave][li][0];
        uint32_t v1 = lv[wave][16 + li][0];
        uint32_t v2 = lv[wave][32 + li][0];
        uint32_t v3 = lv[wave][48 + li][0];
        uint32_t* ov = pkey + (((size_t)m * JC + chunk) * NROW + i) * KSEL;
        uint16_t* oi = pidx + (((size_t)m * JC + chunk) * NROW + i) * KSEL;
        #pragma unroll
        for (int t = 0; t < KSEL; ++t) {
            uint32_t bv = v0; int bg = 0;
            if (v1 > bv) { bv = v1; bg = 1; }
            if (v2 > bv) { bv = v2; bg = 2; }
            if (v3 > bv) { bv = v3; bg = 3; }
            const uint32_t id = bv & 1023u;
            const int j = (t0 + (int)(id >> 2)) * 16 + bg * 4 + (int)(id & 3u);
            if      (bg == 0) { p0++; v0 = p0 < KSEL ? lv[wave][li][p0]      : 0u; }
            else if (bg == 1) { p1++; v1 = p1 < KSEL ? lv[wave][16 + li][p1] : 0u; }
            else if (bg == 2) { p2++; v2 = p2 < KSEL ? lv[wave][32 + li][p2] : 0u; }
            else              { p3++; v3 = p3 < KSEL ? lv[wave][48 + li][p3] : 0u; }
            ov[t] = bv; oi[t] = (uint16_t)j;
        }
    }
}

// ---------------------------------------------------------------- merge + count
template<int JC>
__global__ __launch_bounds__(256)
void knn_merge_count(const uint32_t* __restrict__ pkey, const uint16_t* __restrict__ pidx,
                     unsigned* __restrict__ counter)
{
    __shared__ int wsum[4];
    const int i    = blockIdx.x * 256 + threadIdx.x;
    const int lane = threadIdx.x & 63;
    const int wave = threadIdx.x >> 6;

    int cnt = 0;
    if (i < NROW) {
        int ids[2][KSEL];
        #pragma unroll
        for (int m = 0; m < 2; ++m) {
            const uint32_t* pv = pkey + (size_t)m * JC * NROW * KSEL;
            const uint16_t* px = pidx + (size_t)m * JC * NROW * KSEL;
            uint32_t v[JC]; int p[JC];
            #pragma unroll
            for (int gg = 0; gg < JC; ++gg) {
                p[gg] = 0;
                v[gg] = pv[((size_t)gg * NROW + i) * KSEL];
            }
            #pragma unroll
            for (int t = 0; t < KSEL; ++t) {
                uint32_t bv = v[0]; int bg = 0;
                #pragma unroll
                for (int gg = 1; gg < JC; ++gg) if (v[gg] > bv) { bv = v[gg]; bg = gg; }
                int j = 0;
                #pragma unroll
                for (int gg = 0; gg < JC; ++gg)
                    if (gg == bg) j = (int)px[((size_t)gg * NROW + i) * KSEL + p[gg]];
                ids[m][t] = j;
                #pragma unroll
                for (int gg = 0; gg < JC; ++gg)
                    if (gg == bg) {
                        p[gg]++;
                        v[gg] = p[gg] < KSEL ? pv[((size_t)gg * NROW + i) * KSEL + p[gg]] : 0u;
                    }
            }
        }
        #pragma unroll
        for (int a = 0; a < KSEL; ++a)
            #pragma unroll
            for (int b = 0; b < KSEL; ++b)
                cnt += (ids[0][a] == ids[1][b]) ? 1 : 0;
    }

    #pragma unroll
    for (int off = 32; off; off >>= 1) cnt += __shfl_down(cnt, off);
    if (lane == 0) wsum[wave] = cnt;
    __syncthreads();
    if (threadIdx.x == 0)
        atomicAdd(counter, (unsigned)(wsum[0] + wsum[1] + wsum[2] + wsum[3]));
}

__global__ void knn_finalize(const unsigned* __restrict__ counter, float* __restrict__ out)
{
    out[0] = 1.0f - (float)(*counter) / (float)(NROW * KSEL);
}

// ---------------------------------------------------------------- launch
#define XPAD (4 * 2048)   // prefetch overrun pad (elements)
#define SQPAD 128         // sq prefetch overrun pad (floats)

static size_t ws_need(int jc)
{
    size_t o = ((size_t)2 * NP * DIM + XPAD) * sizeof(bf16_t)
             + ((size_t)2 * NP + SQPAD) * sizeof(float);
    o = (o + 255) & ~(size_t)255;
    o += (size_t)2 * jc * NROW * KSEL * sizeof(uint32_t);
    o += (size_t)2 * jc * NROW * KSEL * sizeof(uint16_t);
    o = (o + 255) & ~(size_t)255;
    o += 256;
    return o;
}

extern "C" void kernel_launch(void* const* d_in, const int* in_sizes, int n_in,
                              void* d_out, int out_size, void* d_ws, size_t ws_size,
                              hipStream_t stream)
{
    (void)in_sizes; (void)n_in; (void)out_size;
    const float* x0 = (const float*)d_in[0];
    const float* x1 = (const float*)d_in[1];
    float* out = (float*)d_out;

    const int jc = (ws_size >= ws_need(8)) ? 8 : 4;

    char* ws = (char*)d_ws;
    size_t off = 0;
    bf16_t* xp  = (bf16_t*)(ws + off); off += ((size_t)2 * NP * DIM + XPAD) * sizeof(bf16_t);
    float*  sqh = (float*)(ws + off);  off += ((size_t)2 * NP + SQPAD) * sizeof(float);
    off = (off + 255) & ~(size_t)255;
    uint32_t* pkey = (uint32_t*)(ws + off); off += (size_t)2 * jc * NROW * KSEL * sizeof(uint32_t);
    uint16_t* pidx = (uint16_t*)(ws + off); off += (size_t)2 * jc * NROW * KSEL * sizeof(uint16_t);
    off = (off + 255) & ~(size_t)255;
    unsigned* counter = (unsigned*)(ws + off);

    knn_convert<<<(2 * NP) / 4, 256, 0, stream>>>(x0, x1, xp, sqh, counter);
    if (jc == 8) {
        knn_topk<8><<<dim3(NP / 64, 8, 2), 256, 0, stream>>>(xp, sqh, pkey, pidx);
        knn_merge_count<8><<<(NROW + 255) / 256, 256, 0, stream>>>(pkey, pidx, counter);
    } else {
        knn_topk<4><<<dim3(NP / 64, 4, 2), 256, 0, stream>>>(xp, sqh, pkey, pidx);
        knn_merge_count<4><<<(NROW + 255) / 256, 256, 0, stream>>>(pkey, pidx, counter);
    }
    knn_finalize<<<1, 1, 0, stream>>>(counter, out);
}

// Round 10
// 204.258 us; speedup vs baseline: 1.0012x; 1.0012x over previous
//
#include <hip/hip_runtime.h>
#include <hip/hip_bf16.h>
#include <stdint.h>

#define NROW 10000
#define DIM 128
#define NP 10240          // rows padded to 640 tiles of 16 (divisible by JC=8 chunks)
#define KSEL 15
#define NTILES (NP / 16)  // 640

typedef __attribute__((ext_vector_type(4))) float f32x4;
typedef __attribute__((ext_vector_type(8))) short s16x8;
using bf16_t = __hip_bfloat16;

// ---------------------------------------------------------------- convert
// One wave per row. Writes X in MFMA-fragment-packed layout:
//   elem e = kk*32 + g*8 + pos of row r  ->  ((tile*4+kk)*64 + g*16 + (r&15))*8 + pos
// so an A-fragment load in knn_topk is base + lane*16B (fully coalesced), and
// B-fragments come from the same layout. Also sqh = 1024 - 0.5*|x|^2 (MFMA C-in).
// Pad rows: zero data, sqh = 1.0 -> key ~1.0, never beats real keys (~870+).
__global__ __launch_bounds__(256)
void knn_convert(const float* __restrict__ x0, const float* __restrict__ x1,
                 bf16_t* __restrict__ xp, float* __restrict__ sqh,
                 unsigned* __restrict__ counter)
{
    if (blockIdx.x == 0 && threadIdx.x == 0) *counter = 0u;
    const int rg   = blockIdx.x * 4 + (threadIdx.x >> 6);
    const int lane = threadIdx.x & 63;
    if (rg >= 2 * NP) return;
    const int m = rg >= NP ? 1 : 0;
    const int r = rg - m * NP;
    const float* src = m ? x1 : x0;

    float2 v = make_float2(0.f, 0.f);
    float  s = 0.f;
    if (r < NROW) {
        v = *(const float2*)(src + (size_t)r * DIM + lane * 2);
        s = v.x * v.x + v.y * v.y;
    }
    const uint32_t pk = (uint32_t)__bfloat16_as_ushort(__float2bfloat16(v.x))
                      | ((uint32_t)__bfloat16_as_ushort(__float2bfloat16(v.y)) << 16);
    const int e   = lane * 2;
    const int kk  = e >> 5;
    const int gg  = (e >> 3) & 3;
    const int pos = e & 7;
    const size_t off = ((((size_t)m * NTILES + (r >> 4)) * 4 + kk) * 64
                        + (size_t)(gg * 16 + (r & 15))) * 8 + pos;   // even
    *(uint32_t*)(xp + off) = pk;
    #pragma unroll
    for (int o = 32; o; o >>= 1) s += __shfl_down(s, o);
    if (lane == 0) sqh[m * NP + r] = (r < NROW) ? fmaf(s, -0.5f, 1024.0f) : 1.0f;
}

// ---------------------------------------------------------------- main
// Key = dot(Xj,Xi) + 1024 - 0.5*sq[j] (bias in MFMA C-in), truncated to 22 bits
// with 10-bit chunk-local index in the low bits (monotonic u32). Branchless
// top-15 per lane: 14x v_med3_u32 + 1 umax in 15 named regs. Modulo-2 software
// pipeline: two register sets (even/odd tiles), each slot computes from its set
// then reloads the SAME variables (no rotation moves); uniform prefetch
// pointers stepped on the scalar pipe; 32-bit lane voffset; no tail clamp
// (xp/sqh over-allocated; overrun prefetches are never consumed).
// launch_bounds(256,2): 256-VGPR budget so ALL state stays in arch VGPRs —
// no v_accvgpr traffic (the round-9 plateau's suspected overhead).
#define INS(k, hi, lo) asm("v_med3_u32 %0, %1, %2, %0" : "+v"(lo) : "v"(k), "v"(hi))

#define INSERT4(acc, idxb)                                                        \
    do {                                                                          \
        _Pragma("unroll")                                                         \
        for (int r_ = 0; r_ < 4; ++r_) {                                          \
            const uint32_t b_ = __float_as_uint((acc)[r_]);                       \
            const uint32_t k_ = (b_ & 0xFFFFFC00u) | ((idxb) | (uint32_t)r_);     \
            INS(k_, q13, q14); INS(k_, q12, q13); INS(k_, q11, q12);              \
            INS(k_, q10, q11); INS(k_, q9,  q10); INS(k_, q8,  q9);               \
            INS(k_, q7,  q8);  INS(k_, q6,  q7);  INS(k_, q5,  q6);               \
            INS(k_, q4,  q5);  INS(k_, q3,  q4);  INS(k_, q2,  q3);               \
            INS(k_, q1,  q2);  INS(k_, q0,  q1);                                  \
            q0 = (q0 > k_) ? q0 : k_;                                             \
        }                                                                         \
    } while (0)

template<int JC>
__global__ __launch_bounds__(256, 2)
void knn_topk(const bf16_t* __restrict__ xp, const float* __restrict__ sqh,
              uint32_t* __restrict__ pkey, uint16_t* __restrict__ pidx)
{
    __shared__ uint32_t lv[4][64][KSEL];   // keys only; j reconstructed from key bits

    const int m     = blockIdx.z;
    const int chunk = blockIdx.y;
    const int ib    = blockIdx.x * 64;
    const int wave  = threadIdx.x >> 6;
    const int lane  = threadIdx.x & 63;
    const int li    = lane & 15;
    const int g     = lane >> 4;

    const bf16_t* XP = xp + (size_t)m * NP * DIM;
    const float*  SQ = sqh + m * NP;

    const int i  = ib + wave * 16 + li;
    const int ti = (ib >> 4) + wave;       // i-tile index for B-fragments

    // B fragments from packed layout: lane holds B[k=kk*32+g*8+e][col=li] = X[i][k]
    s16x8 bfr[4];
    #pragma unroll
    for (int kk = 0; kk < 4; ++kk)
        bfr[kk] = *(const s16x8*)(XP + (((size_t)ti * 4 + kk) * 64 + (size_t)(g * 16 + li)) * 8);

    uint32_t q0 = 0, q1 = 0, q2 = 0, q3 = 0, q4 = 0, q5 = 0, q6 = 0, q7 = 0,
             q8 = 0, q9 = 0, q10 = 0, q11 = 0, q12 = 0, q13 = 0, q14 = 0;

    const int TPC = NTILES / JC;           // tiles per chunk (80 at JC=8, even)
    const int t0  = chunk * TPC;

    const bf16_t* XC = XP + (size_t)t0 * 2048;   // chunk base (uniform)
    const float*  SC = SQ + t0 * 16;             // chunk sq base (uniform)
    const int     la = lane * 8;                 // lane A-frag offset (elements, 16B)
    const int     sg = g * 4;                    // lane sq offset

    // Preload tiles 0 (set A) and 1 (set B); sq issued first (oldest -> counted waits).
    f32x4 sA = *(const f32x4*)(SC + sg);
    s16x8 a0 = *(const s16x8*)(XC + la);
    s16x8 a1 = *(const s16x8*)(XC + la + 512);
    s16x8 a2 = *(const s16x8*)(XC + la + 1024);
    s16x8 a3 = *(const s16x8*)(XC + la + 1536);
    f32x4 sB = *(const f32x4*)(SC + sg + 16);
    s16x8 c0 = *(const s16x8*)(XC + la + 2048);
    s16x8 c1 = *(const s16x8*)(XC + la + 2048 + 512);
    s16x8 c2 = *(const s16x8*)(XC + la + 2048 + 1024);
    s16x8 c3 = *(const s16x8*)(XC + la + 2048 + 1536);

    const bf16_t* pfA = XC + 2 * 2048;   // uniform prefetch base, set A (tile 2p+2)
    const bf16_t* pfB = XC + 3 * 2048;   // set B (tile 2p+3)
    const float*  sfA = SC + 2 * 16;
    const float*  sfB = SC + 3 * 16;

    for (int p = 0; p < TPC / 2; ++p) {
        // ---- slot A: compute tile 2p from set A, then reload set A with tile 2p+2
        {
            f32x4 acc = __builtin_amdgcn_mfma_f32_16x16x32_bf16(a0, bfr[0], sA, 0, 0, 0);
            acc = __builtin_amdgcn_mfma_f32_16x16x32_bf16(a1, bfr[1], acc, 0, 0, 0);
            acc = __builtin_amdgcn_mfma_f32_16x16x32_bf16(a2, bfr[2], acc, 0, 0, 0);
            acc = __builtin_amdgcn_mfma_f32_16x16x32_bf16(a3, bfr[3], acc, 0, 0, 0);
            sA = *(const f32x4*)(sfA + sg);          sfA += 32;
            a0 = *(const s16x8*)(pfA + la);
            a1 = *(const s16x8*)(pfA + la + 512);
            a2 = *(const s16x8*)(pfA + la + 1024);
            a3 = *(const s16x8*)(pfA + la + 1536);   pfA += 4096;
            INSERT4(acc, (uint32_t)(p << 3));
        }
        // ---- slot B: compute tile 2p+1 from set B, then reload set B with tile 2p+3
        {
            f32x4 acc = __builtin_amdgcn_mfma_f32_16x16x32_bf16(c0, bfr[0], sB, 0, 0, 0);
            acc = __builtin_amdgcn_mfma_f32_16x16x32_bf16(c1, bfr[1], acc, 0, 0, 0);
            acc = __builtin_amdgcn_mfma_f32_16x16x32_bf16(c2, bfr[2], acc, 0, 0, 0);
            acc = __builtin_amdgcn_mfma_f32_16x16x32_bf16(c3, bfr[3], acc, 0, 0, 0);
            sB = *(const f32x4*)(sfB + sg);          sfB += 32;
            c0 = *(const s16x8*)(pfB + la);
            c1 = *(const s16x8*)(pfB + la + 512);
            c2 = *(const s16x8*)(pfB + la + 1024);
            c3 = *(const s16x8*)(pfB + la + 1536);   pfB += 4096;
            INSERT4(acc, (uint32_t)(p << 3) | 4u);
        }
    }

    lv[wave][lane][0]  = q0;  lv[wave][lane][1]  = q1;  lv[wave][lane][2]  = q2;
    lv[wave][lane][3]  = q3;  lv[wave][lane][4]  = q4;  lv[wave][lane][5]  = q5;
    lv[wave][lane][6]  = q6;  lv[wave][lane][7]  = q7;  lv[wave][lane][8]  = q8;
    lv[wave][lane][9]  = q9;  lv[wave][lane][10] = q10; lv[wave][lane][11] = q11;
    lv[wave][lane][12] = q12; lv[wave][lane][13] = q13; lv[wave][lane][14] = q14;
    __syncthreads();

    // 4-way merge of the lane-group lists for this i; write sorted 15.
    if (g == 0 && i < NROW) {
        int p0 = 0, p1 = 0, p2 = 0, p3 = 0;
        uint32_t v0 = lv[wave][li][0];
        uint32_t v1 = lv[wave][16 + li][0];
        uint32_t v2 = lv[wave][32 + li][0];
        uint32_t v3 = lv[wave][48 + li][0];
        uint32_t* ov = pkey + (((size_t)m * JC + chunk) * NROW + i) * KSEL;
        uint16_t* oi = pidx + (((size_t)m * JC + chunk) * NROW + i) * KSEL;
        #pragma unroll
        for (int t = 0; t < KSEL; ++t) {
            uint32_t bv = v0; int bg = 0;
            if (v1 > bv) { bv = v1; bg = 1; }
            if (v2 > bv) { bv = v2; bg = 2; }
            if (v3 > bv) { bv = v3; bg = 3; }
            const uint32_t id = bv & 1023u;
            const int j = (t0 + (int)(id >> 2)) * 16 + bg * 4 + (int)(id & 3u);
            if      (bg == 0) { p0++; v0 = p0 < KSEL ? lv[wave][li][p0]      : 0u; }
            else if (bg == 1) { p1++; v1 = p1 < KSEL ? lv[wave][16 + li][p1] : 0u; }
            else if (bg == 2) { p2++; v2 = p2 < KSEL ? lv[wave][32 + li][p2] : 0u; }
            else              { p3++; v3 = p3 < KSEL ? lv[wave][48 + li][p3] : 0u; }
            ov[t] = bv; oi[t] = (uint16_t)j;
        }
    }
}

// ---------------------------------------------------------------- merge + count
template<int JC>
__global__ __launch_bounds__(256)
void knn_merge_count(const uint32_t* __restrict__ pkey, const uint16_t* __restrict__ pidx,
                     unsigned* __restrict__ counter)
{
    __shared__ int wsum[4];
    const int i    = blockIdx.x * 256 + threadIdx.x;
    const int lane = threadIdx.x & 63;
    const int wave = threadIdx.x >> 6;

    int cnt = 0;
    if (i < NROW) {
        int ids[2][KSEL];
        #pragma unroll
        for (int m = 0; m < 2; ++m) {
            const uint32_t* pv = pkey + (size_t)m * JC * NROW * KSEL;
            const uint16_t* px = pidx + (size_t)m * JC * NROW * KSEL;
            uint32_t v[JC]; int p[JC];
            #pragma unroll
            for (int gg = 0; gg < JC; ++gg) {
                p[gg] = 0;
                v[gg] = pv[((size_t)gg * NROW + i) * KSEL];
            }
            #pragma unroll
            for (int t = 0; t < KSEL; ++t) {
                uint32_t bv = v[0]; int bg = 0;
                #pragma unroll
                for (int gg = 1; gg < JC; ++gg) if (v[gg] > bv) { bv = v[gg]; bg = gg; }
                int j = 0;
                #pragma unroll
                for (int gg = 0; gg < JC; ++gg)
                    if (gg == bg) j = (int)px[((size_t)gg * NROW + i) * KSEL + p[gg]];
                ids[m][t] = j;
                #pragma unroll
                for (int gg = 0; gg < JC; ++gg)
                    if (gg == bg) {
                        p[gg]++;
                        v[gg] = p[gg] < KSEL ? pv[((size_t)gg * NROW + i) * KSEL + p[gg]] : 0u;
                    }
            }
        }
        #pragma unroll
        for (int a = 0; a < KSEL; ++a)
            #pragma unroll
            for (int b = 0; b < KSEL; ++b)
                cnt += (ids[0][a] == ids[1][b]) ? 1 : 0;
    }

    #pragma unroll
    for (int off = 32; off; off >>= 1) cnt += __shfl_down(cnt, off);
    if (lane == 0) wsum[wave] = cnt;
    __syncthreads();
    if (threadIdx.x == 0)
        atomicAdd(counter, (unsigned)(wsum[0] + wsum[1] + wsum[2] + wsum[3]));
}

__global__ void knn_finalize(const unsigned* __restrict__ counter, float* __restrict__ out)
{
    out[0] = 1.0f - (float)(*counter) / (float)(NROW * KSEL);
}

// ---------------------------------------------------------------- launch
#define XPAD (4 * 2048)   // prefetch overrun pad (elements)
#define SQPAD 128         // sq prefetch overrun pad (floats)

static size_t ws_need(int jc)
{
    size_t o = ((size_t)2 * NP * DIM + XPAD) * sizeof(bf16_t)
             + ((size_t)2 * NP + SQPAD) * sizeof(float);
    o = (o + 255) & ~(size_t)255;
    o += (size_t)2 * jc * NROW * KSEL * sizeof(uint32_t);
    o += (size_t)2 * jc * NROW * KSEL * sizeof(uint16_t);
    o = (o + 255) & ~(size_t)255;
    o += 256;
    return o;
}

extern "C" void kernel_launch(void* const* d_in, const int* in_sizes, int n_in,
                              void* d_out, int out_size, void* d_ws, size_t ws_size,
                              hipStream_t stream)
{
    (void)in_sizes; (void)n_in; (void)out_size;
    const float* x0 = (const float*)d_in[0];
    const float* x1 = (const float*)d_in[1];
    float* out = (float*)d_out;

    const int jc = (ws_size >= ws_need(8)) ? 8 : 4;

    char* ws = (char*)d_ws;
    size_t off = 0;
    bf16_t* xp  = (bf16_t*)(ws + off); off += ((size_t)2 * NP * DIM + XPAD) * sizeof(bf16_t);
    float*  sqh = (float*)(ws + off);  off += ((size_t)2 * NP + SQPAD) * sizeof(float);
    off = (off + 255) & ~(size_t)255;
    uint32_t* pkey = (uint32_t*)(ws + off); off += (size_t)2 * jc * NROW * KSEL * sizeof(uint32_t);
    uint16_t* pidx = (uint16_t*)(ws + off); off += (size_t)2 * jc * NROW * KSEL * sizeof(uint16_t);
    off = (off + 255) & ~(size_t)255;
    unsigned* counter = (unsigned*)(ws + off);

    knn_convert<<<(2 * NP) / 4, 256, 0, stream>>>(x0, x1, xp, sqh, counter);
    if (jc == 8) {
        knn_topk<8><<<dim3(NP / 64, 8, 2), 256, 0, stream>>>(xp, sqh, pkey, pidx);
        knn_merge_count<8><<<(NROW + 255) / 256, 256, 0, stream>>>(pkey, pidx, counter);
    } else {
        knn_topk<4><<<dim3(NP / 64, 4, 2), 256, 0, stream>>>(xp, sqh, pkey, pidx);
        knn_merge_count<4><<<(NROW + 255) / 256, 256, 0, stream>>>(pkey, pidx, counter);
    }
    knn_finalize<<<1, 1, 0, stream>>>(counter, out);
}

// Round 11
// 188.229 us; speedup vs baseline: 1.0865x; 1.0852x over previous
//
#include <hip/hip_runtime.h>
#include <hip/hip_bf16.h>
#include <stdint.h>

#define NROW 10000
#define DIM 128
#define NP 10240          // rows padded to 640 tiles of 16 (divisible by JC=8 chunks)
#define KSEL 15
#define LCAP 4            // per-lane top-list capacity (see capacity-miss analysis)
#define NTILES (NP / 16)  // 640

typedef __attribute__((ext_vector_type(4))) float f32x4;
typedef __attribute__((ext_vector_type(8))) short s16x8;
using bf16_t = __hip_bfloat16;

// ---------------------------------------------------------------- convert
// One wave per row. Writes X in MFMA-fragment-packed layout:
//   elem e = kk*32 + g*8 + pos of row r  ->  ((tile*4+kk)*64 + g*16 + (r&15))*8 + pos
// so an A-fragment load in knn_topk is base + lane*16B (fully coalesced), and
// B-fragments come from the same layout. Also sqh = 1024 - 0.5*|x|^2 (MFMA C-in).
// Pad rows: zero data, sqh = 1.0 -> key ~1.0, never beats real keys (~870+).
__global__ __launch_bounds__(256)
void knn_convert(const float* __restrict__ x0, const float* __restrict__ x1,
                 bf16_t* __restrict__ xp, float* __restrict__ sqh,
                 unsigned* __restrict__ counter)
{
    if (blockIdx.x == 0 && threadIdx.x == 0) *counter = 0u;
    const int rg   = blockIdx.x * 4 + (threadIdx.x >> 6);
    const int lane = threadIdx.x & 63;
    if (rg >= 2 * NP) return;
    const int m = rg >= NP ? 1 : 0;
    const int r = rg - m * NP;
    const float* src = m ? x1 : x0;

    float2 v = make_float2(0.f, 0.f);
    float  s = 0.f;
    if (r < NROW) {
        v = *(const float2*)(src + (size_t)r * DIM + lane * 2);
        s = v.x * v.x + v.y * v.y;
    }
    const uint32_t pk = (uint32_t)__bfloat16_as_ushort(__float2bfloat16(v.x))
                      | ((uint32_t)__bfloat16_as_ushort(__float2bfloat16(v.y)) << 16);
    const int e   = lane * 2;
    const int kk  = e >> 5;
    const int gg  = (e >> 3) & 3;
    const int pos = e & 7;
    const size_t off = ((((size_t)m * NTILES + (r >> 4)) * 4 + kk) * 64
                        + (size_t)(gg * 16 + (r & 15))) * 8 + pos;   // even
    *(uint32_t*)(xp + off) = pk;
    #pragma unroll
    for (int o = 32; o; o >>= 1) s += __shfl_down(s, o);
    if (lane == 0) sqh[m * NP + r] = (r < NROW) ? fmaf(s, -0.5f, 1024.0f) : 1.0f;
}

// ---------------------------------------------------------------- main
// Key = dot(Xj,Xi) + 1024 - 0.5*sq[j] (bias in MFMA C-in), truncated to 22 bits
// with 10-bit chunk-local index in the low bits (monotonic u32). Branchless
// top-4 per lane (capacity-miss analysis: P(>4 of row's true top-15 in one
// (chunk,group) cell) ~ 9e-5 -> expected loss error ~3e-5 << 1.87e-2 threshold):
// 3x v_med3_u32 + 1 umax per key in 4 named regs. Modulo-2 software pipeline:
// two register sets (even/odd tiles), each slot computes from its set then
// reloads the SAME variables; uniform prefetch pointers stepped on the scalar
// pipe; 32-bit lane voffset; no tail clamp (xp/sqh over-allocated; overrun
// prefetches never consumed). Per-chunk output = top-15 of the 4x4 merged.
#define INS(k, hi, lo) asm("v_med3_u32 %0, %1, %2, %0" : "+v"(lo) : "v"(k), "v"(hi))

#define INSERT4(acc, idxb)                                                        \
    do {                                                                          \
        _Pragma("unroll")                                                         \
        for (int r_ = 0; r_ < 4; ++r_) {                                          \
            const uint32_t b_ = __float_as_uint((acc)[r_]);                       \
            const uint32_t k_ = (b_ & 0xFFFFFC00u) | ((idxb) | (uint32_t)r_);     \
            INS(k_, q2, q3); INS(k_, q1, q2); INS(k_, q0, q1);                    \
            q0 = (q0 > k_) ? q0 : k_;                                             \
        }                                                                         \
    } while (0)

template<int JC>
__global__ __launch_bounds__(256, 2)
void knn_topk(const bf16_t* __restrict__ xp, const float* __restrict__ sqh,
              uint32_t* __restrict__ pkey, uint16_t* __restrict__ pidx)
{
    __shared__ uint32_t lv[4][64][LCAP];   // keys only; j reconstructed from key bits

    const int m     = blockIdx.z;
    const int chunk = blockIdx.y;
    const int ib    = blockIdx.x * 64;
    const int wave  = threadIdx.x >> 6;
    const int lane  = threadIdx.x & 63;
    const int li    = lane & 15;
    const int g     = lane >> 4;

    const bf16_t* XP = xp + (size_t)m * NP * DIM;
    const float*  SQ = sqh + m * NP;

    const int i  = ib + wave * 16 + li;
    const int ti = (ib >> 4) + wave;       // i-tile index for B-fragments

    // B fragments from packed layout: lane holds B[k=kk*32+g*8+e][col=li] = X[i][k]
    s16x8 bfr[4];
    #pragma unroll
    for (int kk = 0; kk < 4; ++kk)
        bfr[kk] = *(const s16x8*)(XP + (((size_t)ti * 4 + kk) * 64 + (size_t)(g * 16 + li)) * 8);

    uint32_t q0 = 0, q1 = 0, q2 = 0, q3 = 0;

    const int TPC = NTILES / JC;           // tiles per chunk (80 at JC=8, even)
    const int t0  = chunk * TPC;

    const bf16_t* XC = XP + (size_t)t0 * 2048;   // chunk base (uniform)
    const float*  SC = SQ + t0 * 16;             // chunk sq base (uniform)
    const int     la = lane * 8;                 // lane A-frag offset (elements, 16B)
    const int     sg = g * 4;                    // lane sq offset

    // Preload tiles 0 (set A) and 1 (set B); sq issued first (oldest -> counted waits).
    f32x4 sA = *(const f32x4*)(SC + sg);
    s16x8 a0 = *(const s16x8*)(XC + la);
    s16x8 a1 = *(const s16x8*)(XC + la + 512);
    s16x8 a2 = *(const s16x8*)(XC + la + 1024);
    s16x8 a3 = *(const s16x8*)(XC + la + 1536);
    f32x4 sB = *(const f32x4*)(SC + sg + 16);
    s16x8 c0 = *(const s16x8*)(XC + la + 2048);
    s16x8 c1 = *(const s16x8*)(XC + la + 2048 + 512);
    s16x8 c2 = *(const s16x8*)(XC + la + 2048 + 1024);
    s16x8 c3 = *(const s16x8*)(XC + la + 2048 + 1536);

    const bf16_t* pfA = XC + 2 * 2048;   // uniform prefetch base, set A (tile 2p+2)
    const bf16_t* pfB = XC + 3 * 2048;   // set B (tile 2p+3)
    const float*  sfA = SC + 2 * 16;
    const float*  sfB = SC + 3 * 16;

    for (int p = 0; p < TPC / 2; ++p) {
        // ---- slot A: compute tile 2p from set A, then reload set A with tile 2p+2
        {
            f32x4 acc = __builtin_amdgcn_mfma_f32_16x16x32_bf16(a0, bfr[0], sA, 0, 0, 0);
            acc = __builtin_amdgcn_mfma_f32_16x16x32_bf16(a1, bfr[1], acc, 0, 0, 0);
            acc = __builtin_amdgcn_mfma_f32_16x16x32_bf16(a2, bfr[2], acc, 0, 0, 0);
            acc = __builtin_amdgcn_mfma_f32_16x16x32_bf16(a3, bfr[3], acc, 0, 0, 0);
            sA = *(const f32x4*)(sfA + sg);          sfA += 32;
            a0 = *(const s16x8*)(pfA + la);
            a1 = *(const s16x8*)(pfA + la + 512);
            a2 = *(const s16x8*)(pfA + la + 1024);
            a3 = *(const s16x8*)(pfA + la + 1536);   pfA += 4096;
            INSERT4(acc, (uint32_t)(p << 3));
        }
        // ---- slot B: compute tile 2p+1 from set B, then reload set B with tile 2p+3
        {
            f32x4 acc = __builtin_amdgcn_mfma_f32_16x16x32_bf16(c0, bfr[0], sB, 0, 0, 0);
            acc = __builtin_amdgcn_mfma_f32_16x16x32_bf16(c1, bfr[1], acc, 0, 0, 0);
            acc = __builtin_amdgcn_mfma_f32_16x16x32_bf16(c2, bfr[2], acc, 0, 0, 0);
            acc = __builtin_amdgcn_mfma_f32_16x16x32_bf16(c3, bfr[3], acc, 0, 0, 0);
            sB = *(const f32x4*)(sfB + sg);          sfB += 32;
            c0 = *(const s16x8*)(pfB + la);
            c1 = *(const s16x8*)(pfB + la + 512);
            c2 = *(const s16x8*)(pfB + la + 1024);
            c3 = *(const s16x8*)(pfB + la + 1536);   pfB += 4096;
            INSERT4(acc, (uint32_t)(p << 3) | 4u);
        }
    }

    lv[wave][lane][0] = q0;  lv[wave][lane][1] = q1;
    lv[wave][lane][2] = q2;  lv[wave][lane][3] = q3;
    __syncthreads();

    // 4-way merge of the 4 lane-group top-4 lists for this i; write top-15 of 16.
    if (g == 0 && i < NROW) {
        int p0 = 0, p1 = 0, p2 = 0, p3 = 0;
        uint32_t v0 = lv[wave][li][0];
        uint32_t v1 = lv[wave][16 + li][0];
        uint32_t v2 = lv[wave][32 + li][0];
        uint32_t v3 = lv[wave][48 + li][0];
        uint32_t* ov = pkey + (((size_t)m * JC + chunk) * NROW + i) * KSEL;
        uint16_t* oi = pidx + (((size_t)m * JC + chunk) * NROW + i) * KSEL;
        #pragma unroll
        for (int t = 0; t < KSEL; ++t) {
            uint32_t bv = v0; int bg = 0;
            if (v1 > bv) { bv = v1; bg = 1; }
            if (v2 > bv) { bv = v2; bg = 2; }
            if (v3 > bv) { bv = v3; bg = 3; }
            const uint32_t id = bv & 1023u;
            const int j = (t0 + (int)(id >> 2)) * 16 + bg * 4 + (int)(id & 3u);
            if      (bg == 0) { p0++; v0 = p0 < LCAP ? lv[wave][li][p0]      : 0u; }
            else if (bg == 1) { p1++; v1 = p1 < LCAP ? lv[wave][16 + li][p1] : 0u; }
            else if (bg == 2) { p2++; v2 = p2 < LCAP ? lv[wave][32 + li][p2] : 0u; }
            else              { p3++; v3 = p3 < LCAP ? lv[wave][48 + li][p3] : 0u; }
            ov[t] = bv; oi[t] = (uint16_t)j;
        }
    }
}

// ---------------------------------------------------------------- merge + count
template<int JC>
__global__ __launch_bounds__(256)
void knn_merge_count(const uint32_t* __restrict__ pkey, const uint16_t* __restrict__ pidx,
                     unsigned* __restrict__ counter)
{
    __shared__ int wsum[4];
    const int i    = blockIdx.x * 256 + threadIdx.x;
    const int lane = threadIdx.x & 63;
    const int wave = threadIdx.x >> 6;

    int cnt = 0;
    if (i < NROW) {
        int ids[2][KSEL];
        #pragma unroll
        for (int m = 0; m < 2; ++m) {
            const uint32_t* pv = pkey + (size_t)m * JC * NROW * KSEL;
            const uint16_t* px = pidx + (size_t)m * JC * NROW * KSEL;
            uint32_t v[JC]; int p[JC];
            #pragma unroll
            for (int gg = 0; gg < JC; ++gg) {
                p[gg] = 0;
                v[gg] = pv[((size_t)gg * NROW + i) * KSEL];
            }
            #pragma unroll
            for (int t = 0; t < KSEL; ++t) {
                uint32_t bv = v[0]; int bg = 0;
                #pragma unroll
                for (int gg = 1; gg < JC; ++gg) if (v[gg] > bv) { bv = v[gg]; bg = gg; }
                int j = 0;
                #pragma unroll
                for (int gg = 0; gg < JC; ++gg)
                    if (gg == bg) j = (int)px[((size_t)gg * NROW + i) * KSEL + p[gg]];
                ids[m][t] = j;
                #pragma unroll
                for (int gg = 0; gg < JC; ++gg)
                    if (gg == bg) {
                        p[gg]++;
                        v[gg] = p[gg] < KSEL ? pv[((size_t)gg * NROW + i) * KSEL + p[gg]] : 0u;
                    }
            }
        }
        #pragma unroll
        for (int a = 0; a < KSEL; ++a)
            #pragma unroll
            for (int b = 0; b < KSEL; ++b)
                cnt += (ids[0][a] == ids[1][b]) ? 1 : 0;
    }

    #pragma unroll
    for (int off = 32; off; off >>= 1) cnt += __shfl_down(cnt, off);
    if (lane == 0) wsum[wave] = cnt;
    __syncthreads();
    if (threadIdx.x == 0)
        atomicAdd(counter, (unsigned)(wsum[0] + wsum[1] + wsum[2] + wsum[3]));
}

__global__ void knn_finalize(const unsigned* __restrict__ counter, float* __restrict__ out)
{
    out[0] = 1.0f - (float)(*counter) / (float)(NROW * KSEL);
}

// ---------------------------------------------------------------- launch
#define XPAD (4 * 2048)   // prefetch overrun pad (elements)
#define SQPAD 128         // sq prefetch overrun pad (floats)

static size_t ws_need(int jc)
{
    size_t o = ((size_t)2 * NP * DIM + XPAD) * sizeof(bf16_t)
             + ((size_t)2 * NP + SQPAD) * sizeof(float);
    o = (o + 255) & ~(size_t)255;
    o += (size_t)2 * jc * NROW * KSEL * sizeof(uint32_t);
    o += (size_t)2 * jc * NROW * KSEL * sizeof(uint16_t);
    o = (o + 255) & ~(size_t)255;
    o += 256;
    return o;
}

extern "C" void kernel_launch(void* const* d_in, const int* in_sizes, int n_in,
                              void* d_out, int out_size, void* d_ws, size_t ws_size,
                              hipStream_t stream)
{
    (void)in_sizes; (void)n_in; (void)out_size;
    const float* x0 = (const float*)d_in[0];
    const float* x1 = (const float*)d_in[1];
    float* out = (float*)d_out;

    const int jc = (ws_size >= ws_need(8)) ? 8 : 4;

    char* ws = (char*)d_ws;
    size_t off = 0;
    bf16_t* xp  = (bf16_t*)(ws + off); off += ((size_t)2 * NP * DIM + XPAD) * sizeof(bf16_t);
    float*  sqh = (float*)(ws + off);  off += ((size_t)2 * NP + SQPAD) * sizeof(float);
    off = (off + 255) & ~(size_t)255;
    uint32_t* pkey = (uint32_t*)(ws + off); off += (size_t)2 * jc * NROW * KSEL * sizeof(uint32_t);
    uint16_t* pidx = (uint16_t*)(ws + off); off += (size_t)2 * jc * NROW * KSEL * sizeof(uint16_t);
    off = (off + 255) & ~(size_t)255;
    unsigned* counter = (unsigned*)(ws + off);

    knn_convert<<<(2 * NP) / 4, 256, 0, stream>>>(x0, x1, xp, sqh, counter);
    if (jc == 8) {
        knn_topk<8><<<dim3(NP / 64, 8, 2), 256, 0, stream>>>(xp, sqh, pkey, pidx);
        knn_merge_count<8><<<(NROW + 255) / 256, 256, 0, stream>>>(pkey, pidx, counter);
    } else {
        knn_topk<4><<<dim3(NP / 64, 4, 2), 256, 0, stream>>>(xp, sqh, pkey, pidx);
        knn_merge_count<4><<<(NROW + 255) / 256, 256, 0, stream>>>(pkey, pidx, counter);
    }
    knn_finalize<<<1, 1, 0, stream>>>(counter, out);
}

// Round 12
// 135.608 us; speedup vs baseline: 1.5081x; 1.3880x over previous
//
#include <hip/hip_runtime.h>
#include <hip/hip_bf16.h>
#include <stdint.h>

#define NROW 10000
#define DIM 128
#define NP 10240          // rows padded to 640 tiles of 16 (divisible by JC=8 chunks)
#define KSEL 15
#define LCAP 4            // per-lane top-list capacity (capacity-miss analysis: ~9e-5)
#define NTILES (NP / 16)  // 640

typedef __attribute__((ext_vector_type(4))) float f32x4;
typedef __attribute__((ext_vector_type(8))) short s16x8;
using bf16_t = __hip_bfloat16;

// ---------------------------------------------------------------- convert
// One wave per row. Writes X in MFMA-fragment-packed layout:
//   elem e = kk*32 + g*8 + pos of row r  ->  ((tile*4+kk)*64 + g*16 + (r&15))*8 + pos
// so an A-fragment load in knn_topk is base + lane*16B (fully coalesced), and
// B-fragments come from the same layout. Also sqh = 1024 - 0.5*|x|^2 (MFMA C-in).
// Pad rows: zero data, sqh = 1.0 -> key ~1.0, never beats real keys (~870+).
__global__ __launch_bounds__(256)
void knn_convert(const float* __restrict__ x0, const float* __restrict__ x1,
                 bf16_t* __restrict__ xp, float* __restrict__ sqh,
                 unsigned* __restrict__ counter)
{
    if (blockIdx.x == 0 && threadIdx.x == 0) *counter = 0u;
    const int rg   = blockIdx.x * 4 + (threadIdx.x >> 6);
    const int lane = threadIdx.x & 63;
    if (rg >= 2 * NP) return;
    const int m = rg >= NP ? 1 : 0;
    const int r = rg - m * NP;
    const float* src = m ? x1 : x0;

    float2 v = make_float2(0.f, 0.f);
    float  s = 0.f;
    if (r < NROW) {
        v = *(const float2*)(src + (size_t)r * DIM + lane * 2);
        s = v.x * v.x + v.y * v.y;
    }
    const uint32_t pk = (uint32_t)__bfloat16_as_ushort(__float2bfloat16(v.x))
                      | ((uint32_t)__bfloat16_as_ushort(__float2bfloat16(v.y)) << 16);
    const int e   = lane * 2;
    const int kk  = e >> 5;
    const int gg  = (e >> 3) & 3;
    const int pos = e & 7;
    const size_t off = ((((size_t)m * NTILES + (r >> 4)) * 4 + kk) * 64
                        + (size_t)(gg * 16 + (r & 15))) * 8 + pos;   // even
    *(uint32_t*)(xp + off) = pk;
    #pragma unroll
    for (int o = 32; o; o >>= 1) s += __shfl_down(s, o);
    if (lane == 0) sqh[m * NP + r] = (r < NROW) ? fmaf(s, -0.5f, 1024.0f) : 1.0f;
}

// ---------------------------------------------------------------- main
// Key = dot(Xj,Xi) + 1024 - 0.5*sq[j] (bias in MFMA C-in), truncated to 22 bits
// with 10-bit chunk-local index in the low bits (monotonic u32). Branchless
// top-4 per lane per i-set: 3x v_med3_u32 + 1 umax per key, two lists (dual-B).
// DUAL B-TILES: each wave holds B-fragments for TWO i-tiles (32 i / wave,
// 128 i / block) and feeds both from the same A-fragments -> load bytes per
// key halve (L1/TA relief) and blocks per chunk halve (L2 traffic 3.3->1.65GB).
// Modulo-2 software pipeline: two A-register sets (even/odd tiles), each slot
// computes from its set then reloads the SAME variables; uniform prefetch
// pointers stepped on the scalar pipe; no tail clamp (xp/sqh over-allocated).
#define INS(k, hi, lo) asm("v_med3_u32 %0, %1, %2, %0" : "+v"(lo) : "v"(k), "v"(hi))

#define INSERT4(acc, idxb, Q0, Q1, Q2, Q3)                                        \
    do {                                                                          \
        _Pragma("unroll")                                                         \
        for (int r_ = 0; r_ < 4; ++r_) {                                          \
            const uint32_t b_ = __float_as_uint((acc)[r_]);                       \
            const uint32_t k_ = (b_ & 0xFFFFFC00u) | ((idxb) | (uint32_t)r_);     \
            INS(k_, Q2, Q3); INS(k_, Q1, Q2); INS(k_, Q0, Q1);                    \
            Q0 = (Q0 > k_) ? Q0 : k_;                                             \
        }                                                                         \
    } while (0)

template<int JC>
__global__ __launch_bounds__(256, 2)
void knn_topk(const bf16_t* __restrict__ xp, const float* __restrict__ sqh,
              uint32_t* __restrict__ pkey, uint16_t* __restrict__ pidx)
{
    __shared__ uint32_t lv[4][64][2][LCAP];   // [wave][lane][i-set][slot], 8 KB

    const int m     = blockIdx.z;
    const int chunk = blockIdx.y;
    const int ib    = blockIdx.x * 128;
    const int wave  = threadIdx.x >> 6;
    const int lane  = threadIdx.x & 63;
    const int li    = lane & 15;
    const int g     = lane >> 4;

    const bf16_t* XP = xp + (size_t)m * NP * DIM;
    const float*  SQ = sqh + m * NP;

    const int ti0 = (ib >> 4) + wave * 2;   // first of this wave's two i-tiles

    // B fragments for both i-sets: lane holds B[k=kk*32+g*8+e][col=li] = X[i][k]
    s16x8 bfr0[4], bfr1[4];
    #pragma unroll
    for (int kk = 0; kk < 4; ++kk) {
        bfr0[kk] = *(const s16x8*)(XP + (((size_t)ti0 * 4 + kk) * 64 + (size_t)(g * 16 + li)) * 8);
        bfr1[kk] = *(const s16x8*)(XP + (((size_t)(ti0 + 1) * 4 + kk) * 64 + (size_t)(g * 16 + li)) * 8);
    }

    uint32_t q0 = 0, q1 = 0, q2 = 0, q3 = 0;   // top-4, i-set 0
    uint32_t r0 = 0, r1 = 0, r2 = 0, r3 = 0;   // top-4, i-set 1

    const int TPC = NTILES / JC;           // tiles per chunk (80 at JC=8, even)
    const int t0  = chunk * TPC;

    const bf16_t* XC = XP + (size_t)t0 * 2048;   // chunk base (uniform)
    const float*  SC = SQ + t0 * 16;             // chunk sq base (uniform)
    const int     la = lane * 8;                 // lane A-frag offset (elements, 16B)
    const int     sg = g * 4;                    // lane sq offset

    // Preload tiles 0 (set A) and 1 (set B); sq issued first (oldest -> counted waits).
    f32x4 sA = *(const f32x4*)(SC + sg);
    s16x8 a0 = *(const s16x8*)(XC + la);
    s16x8 a1 = *(const s16x8*)(XC + la + 512);
    s16x8 a2 = *(const s16x8*)(XC + la + 1024);
    s16x8 a3 = *(const s16x8*)(XC + la + 1536);
    f32x4 sB = *(const f32x4*)(SC + sg + 16);
    s16x8 c0 = *(const s16x8*)(XC + la + 2048);
    s16x8 c1 = *(const s16x8*)(XC + la + 2048 + 512);
    s16x8 c2 = *(const s16x8*)(XC + la + 2048 + 1024);
    s16x8 c3 = *(const s16x8*)(XC + la + 2048 + 1536);

    const bf16_t* pfA = XC + 2 * 2048;   // uniform prefetch base, set A (tile 2p+2)
    const bf16_t* pfB = XC + 3 * 2048;   // set B (tile 2p+3)
    const float*  sfA = SC + 2 * 16;
    const float*  sfB = SC + 3 * 16;

    for (int p = 0; p < TPC / 2; ++p) {
        // ---- slot A: compute tile 2p (both i-sets), reload set A with tile 2p+2
        {
            f32x4 acc0 = __builtin_amdgcn_mfma_f32_16x16x32_bf16(a0, bfr0[0], sA, 0, 0, 0);
            f32x4 acc1 = __builtin_amdgcn_mfma_f32_16x16x32_bf16(a0, bfr1[0], sA, 0, 0, 0);
            acc0 = __builtin_amdgcn_mfma_f32_16x16x32_bf16(a1, bfr0[1], acc0, 0, 0, 0);
            acc1 = __builtin_amdgcn_mfma_f32_16x16x32_bf16(a1, bfr1[1], acc1, 0, 0, 0);
            acc0 = __builtin_amdgcn_mfma_f32_16x16x32_bf16(a2, bfr0[2], acc0, 0, 0, 0);
            acc1 = __builtin_amdgcn_mfma_f32_16x16x32_bf16(a2, bfr1[2], acc1, 0, 0, 0);
            acc0 = __builtin_amdgcn_mfma_f32_16x16x32_bf16(a3, bfr0[3], acc0, 0, 0, 0);
            acc1 = __builtin_amdgcn_mfma_f32_16x16x32_bf16(a3, bfr1[3], acc1, 0, 0, 0);
            sA = *(const f32x4*)(sfA + sg);          sfA += 32;
            a0 = *(const s16x8*)(pfA + la);
            a1 = *(const s16x8*)(pfA + la + 512);
            a2 = *(const s16x8*)(pfA + la + 1024);
            a3 = *(const s16x8*)(pfA + la + 1536);   pfA += 4096;
            const uint32_t ib4 = (uint32_t)(p << 3);
            INSERT4(acc0, ib4, q0, q1, q2, q3);
            INSERT4(acc1, ib4, r0, r1, r2, r3);
        }
        // ---- slot B: compute tile 2p+1 (both i-sets), reload set B with tile 2p+3
        {
            f32x4 acc0 = __builtin_amdgcn_mfma_f32_16x16x32_bf16(c0, bfr0[0], sB, 0, 0, 0);
            f32x4 acc1 = __builtin_amdgcn_mfma_f32_16x16x32_bf16(c0, bfr1[0], sB, 0, 0, 0);
            acc0 = __builtin_amdgcn_mfma_f32_16x16x32_bf16(c1, bfr0[1], acc0, 0, 0, 0);
            acc1 = __builtin_amdgcn_mfma_f32_16x16x32_bf16(c1, bfr1[1], acc1, 0, 0, 0);
            acc0 = __builtin_amdgcn_mfma_f32_16x16x32_bf16(c2, bfr0[2], acc0, 0, 0, 0);
            acc1 = __builtin_amdgcn_mfma_f32_16x16x32_bf16(c2, bfr1[2], acc1, 0, 0, 0);
            acc0 = __builtin_amdgcn_mfma_f32_16x16x32_bf16(c3, bfr0[3], acc0, 0, 0, 0);
            acc1 = __builtin_amdgcn_mfma_f32_16x16x32_bf16(c3, bfr1[3], acc1, 0, 0, 0);
            sB = *(const f32x4*)(sfB + sg);          sfB += 32;
            c0 = *(const s16x8*)(pfB + la);
            c1 = *(const s16x8*)(pfB + la + 512);
            c2 = *(const s16x8*)(pfB + la + 1024);
            c3 = *(const s16x8*)(pfB + la + 1536);   pfB += 4096;
            const uint32_t ib4 = (uint32_t)(p << 3) | 4u;
            INSERT4(acc0, ib4, q0, q1, q2, q3);
            INSERT4(acc1, ib4, r0, r1, r2, r3);
        }
    }

    lv[wave][lane][0][0] = q0;  lv[wave][lane][0][1] = q1;
    lv[wave][lane][0][2] = q2;  lv[wave][lane][0][3] = q3;
    lv[wave][lane][1][0] = r0;  lv[wave][lane][1][1] = r1;
    lv[wave][lane][1][2] = r2;  lv[wave][lane][1][3] = r3;
    __syncthreads();

    // 4-way merge of the 4 lane-group top-4 lists; lanes g<2 each handle i-set s=g.
    if (g < 2) {
        const int s = g;
        const int i = ib + wave * 32 + s * 16 + li;
        if (i < NROW) {
            int p0 = 0, p1 = 0, p2 = 0, p3 = 0;
            uint32_t v0 = lv[wave][li][s][0];
            uint32_t v1 = lv[wave][16 + li][s][0];
            uint32_t v2 = lv[wave][32 + li][s][0];
            uint32_t v3 = lv[wave][48 + li][s][0];
            uint32_t* ov = pkey + (((size_t)m * JC + chunk) * NROW + i) * KSEL;
            uint16_t* oi = pidx + (((size_t)m * JC + chunk) * NROW + i) * KSEL;
            #pragma unroll
            for (int t = 0; t < KSEL; ++t) {
                uint32_t bv = v0; int bg = 0;
                if (v1 > bv) { bv = v1; bg = 1; }
                if (v2 > bv) { bv = v2; bg = 2; }
                if (v3 > bv) { bv = v3; bg = 3; }
                const uint32_t id = bv & 1023u;
                const int j = (t0 + (int)(id >> 2)) * 16 + bg * 4 + (int)(id & 3u);
                if      (bg == 0) { p0++; v0 = p0 < LCAP ? lv[wave][li][s][p0]      : 0u; }
                else if (bg == 1) { p1++; v1 = p1 < LCAP ? lv[wave][16 + li][s][p1] : 0u; }
                else if (bg == 2) { p2++; v2 = p2 < LCAP ? lv[wave][32 + li][s][p2] : 0u; }
                else              { p3++; v3 = p3 < LCAP ? lv[wave][48 + li][s][p3] : 0u; }
                ov[t] = bv; oi[t] = (uint16_t)j;
            }
        }
    }
}

// ---------------------------------------------------------------- merge + count
template<int JC>
__global__ __launch_bounds__(256)
void knn_merge_count(const uint32_t* __restrict__ pkey, const uint16_t* __restrict__ pidx,
                     unsigned* __restrict__ counter)
{
    __shared__ int wsum[4];
    const int i    = blockIdx.x * 256 + threadIdx.x;
    const int lane = threadIdx.x & 63;
    const int wave = threadIdx.x >> 6;

    int cnt = 0;
    if (i < NROW) {
        int ids[2][KSEL];
        #pragma unroll
        for (int m = 0; m < 2; ++m) {
            const uint32_t* pv = pkey + (size_t)m * JC * NROW * KSEL;
            const uint16_t* px = pidx + (size_t)m * JC * NROW * KSEL;
            uint32_t v[JC]; int p[JC];
            #pragma unroll
            for (int gg = 0; gg < JC; ++gg) {
                p[gg] = 0;
                v[gg] = pv[((size_t)gg * NROW + i) * KSEL];
            }
            #pragma unroll
            for (int t = 0; t < KSEL; ++t) {
                uint32_t bv = v[0]; int bg = 0;
                #pragma unroll
                for (int gg = 1; gg < JC; ++gg) if (v[gg] > bv) { bv = v[gg]; bg = gg; }
                int j = 0;
                #pragma unroll
                for (int gg = 0; gg < JC; ++gg)
                    if (gg == bg) j = (int)px[((size_t)gg * NROW + i) * KSEL + p[gg]];
                ids[m][t] = j;
                #pragma unroll
                for (int gg = 0; gg < JC; ++gg)
                    if (gg == bg) {
                        p[gg]++;
                        v[gg] = p[gg] < KSEL ? pv[((size_t)gg * NROW + i) * KSEL + p[gg]] : 0u;
                    }
            }
        }
        #pragma unroll
        for (int a = 0; a < KSEL; ++a)
            #pragma unroll
            for (int b = 0; b < KSEL; ++b)
                cnt += (ids[0][a] == ids[1][b]) ? 1 : 0;
    }

    #pragma unroll
    for (int off = 32; off; off >>= 1) cnt += __shfl_down(cnt, off);
    if (lane == 0) wsum[wave] = cnt;
    __syncthreads();
    if (threadIdx.x == 0)
        atomicAdd(counter, (unsigned)(wsum[0] + wsum[1] + wsum[2] + wsum[3]));
}

__global__ void knn_finalize(const unsigned* __restrict__ counter, float* __restrict__ out)
{
    out[0] = 1.0f - (float)(*counter) / (float)(NROW * KSEL);
}

// ---------------------------------------------------------------- launch
#define XPAD (4 * 2048)   // prefetch overrun pad (elements)
#define SQPAD 128         // sq prefetch overrun pad (floats)

static size_t ws_need(int jc)
{
    size_t o = ((size_t)2 * NP * DIM + XPAD) * sizeof(bf16_t)
             + ((size_t)2 * NP + SQPAD) * sizeof(float);
    o = (o + 255) & ~(size_t)255;
    o += (size_t)2 * jc * NROW * KSEL * sizeof(uint32_t);
    o += (size_t)2 * jc * NROW * KSEL * sizeof(uint16_t);
    o = (o + 255) & ~(size_t)255;
    o += 256;
    return o;
}

extern "C" void kernel_launch(void* const* d_in, const int* in_sizes, int n_in,
                              void* d_out, int out_size, void* d_ws, size_t ws_size,
                              hipStream_t stream)
{
    (void)in_sizes; (void)n_in; (void)out_size;
    const float* x0 = (const float*)d_in[0];
    const float* x1 = (const float*)d_in[1];
    float* out = (float*)d_out;

    const int jc = (ws_size >= ws_need(8)) ? 8 : 4;

    char* ws = (char*)d_ws;
    size_t off = 0;
    bf16_t* xp  = (bf16_t*)(ws + off); off += ((size_t)2 * NP * DIM + XPAD) * sizeof(bf16_t);
    float*  sqh = (float*)(ws + off);  off += ((size_t)2 * NP + SQPAD) * sizeof(float);
    off = (off + 255) & ~(size_t)255;
    uint32_t* pkey = (uint32_t*)(ws + off); off += (size_t)2 * jc * NROW * KSEL * sizeof(uint32_t);
    uint16_t* pidx = (uint16_t*)(ws + off); off += (size_t)2 * jc * NROW * KSEL * sizeof(uint16_t);
    off = (off + 255) & ~(size_t)255;
    unsigned* counter = (unsigned*)(ws + off);

    knn_convert<<<(2 * NP) / 4, 256, 0, stream>>>(x0, x1, xp, sqh, counter);
    if (jc == 8) {
        knn_topk<8><<<dim3(NP / 128, 8, 2), 256, 0, stream>>>(xp, sqh, pkey, pidx);
        knn_merge_count<8><<<(NROW + 255) / 256, 256, 0, stream>>>(pkey, pidx, counter);
    } else {
        knn_topk<4><<<dim3(NP / 128, 4, 2), 256, 0, stream>>>(xp, sqh, pkey, pidx);
        knn_merge_count<4><<<(NROW + 255) / 256, 256, 0, stream>>>(pkey, pidx, counter);
    }
    knn_finalize<<<1, 1, 0, stream>>>(counter, out);
}

// Round 13
// 134.988 us; speedup vs baseline: 1.5150x; 1.0046x over previous
//
#include <hip/hip_runtime.h>
#include <hip/hip_bf16.h>
#include <stdint.h>

#define NROW 10000
#define DIM 128
#define NP 10240          // rows padded to 640 tiles of 16 (divisible by JC=8 chunks)
#define KSEL 15
#define LCAP 4            // per-lane top-list capacity (capacity-miss analysis: ~9e-5)
#define NTILES (NP / 16)  // 640

typedef __attribute__((ext_vector_type(4))) float f32x4;
typedef __attribute__((ext_vector_type(8))) short s16x8;
using bf16_t = __hip_bfloat16;

// ---------------------------------------------------------------- convert
// One wave per row. Writes X in MFMA-fragment-packed layout:
//   elem e = kk*32 + g*8 + pos of row r  ->  ((tile*4+kk)*64 + g*16 + (r&15))*8 + pos
// so an A-fragment load in knn_topk is base + lane*16B (fully coalesced), and
// B-fragments come from the same layout. Also sqh = 1024 - 0.5*|x|^2 (MFMA C-in).
// Pad rows: zero data, sqh = 1.0 -> key ~1.0, never beats real keys (~870+).
__global__ __launch_bounds__(256)
void knn_convert(const float* __restrict__ x0, const float* __restrict__ x1,
                 bf16_t* __restrict__ xp, float* __restrict__ sqh,
                 unsigned* __restrict__ counter)
{
    if (blockIdx.x == 0 && threadIdx.x == 0) *counter = 0u;
    const int rg   = blockIdx.x * 4 + (threadIdx.x >> 6);
    const int lane = threadIdx.x & 63;
    if (rg >= 2 * NP) return;
    const int m = rg >= NP ? 1 : 0;
    const int r = rg - m * NP;
    const float* src = m ? x1 : x0;

    float2 v = make_float2(0.f, 0.f);
    float  s = 0.f;
    if (r < NROW) {
        v = *(const float2*)(src + (size_t)r * DIM + lane * 2);
        s = v.x * v.x + v.y * v.y;
    }
    const uint32_t pk = (uint32_t)__bfloat16_as_ushort(__float2bfloat16(v.x))
                      | ((uint32_t)__bfloat16_as_ushort(__float2bfloat16(v.y)) << 16);
    const int e   = lane * 2;
    const int kk  = e >> 5;
    const int gg  = (e >> 3) & 3;
    const int pos = e & 7;
    const size_t off = ((((size_t)m * NTILES + (r >> 4)) * 4 + kk) * 64
                        + (size_t)(gg * 16 + (r & 15))) * 8 + pos;   // even
    *(uint32_t*)(xp + off) = pk;
    #pragma unroll
    for (int o = 32; o; o >>= 1) s += __shfl_down(s, o);
    if (lane == 0) sqh[m * NP + r] = (r < NROW) ? fmaf(s, -0.5f, 1024.0f) : 1.0f;
}

// ---------------------------------------------------------------- main
// Key = dot(Xj,Xi) + 1024 - 0.5*sq[j] (bias in MFMA C-in), truncated to 22 bits
// with 10-bit chunk-local index in the low bits (monotonic u32). Branchless
// top-4 per lane per i-set: 3x v_med3_u32 + 1 umax per key, two lists (dual-B).
// DUAL B-TILES: each wave holds B-fragments for TWO i-tiles (32 i / wave,
// 128 i / block), fed from the same A-fragments. Modulo-2 software pipeline.
// Output layout TRANSPOSED (slot-major over i): pkey[((m*JC+chunk)*KSEL+t)*NROW+i]
// so the merge kernel's lane-adjacent rows read coalesced.
#define INS(k, hi, lo) asm("v_med3_u32 %0, %1, %2, %0" : "+v"(lo) : "v"(k), "v"(hi))

#define INSERT4(acc, idxb, Q0, Q1, Q2, Q3)                                        \
    do {                                                                          \
        _Pragma("unroll")                                                         \
        for (int r_ = 0; r_ < 4; ++r_) {                                          \
            const uint32_t b_ = __float_as_uint((acc)[r_]);                       \
            const uint32_t k_ = (b_ & 0xFFFFFC00u) | ((idxb) | (uint32_t)r_);     \
            INS(k_, Q2, Q3); INS(k_, Q1, Q2); INS(k_, Q0, Q1);                    \
            Q0 = (Q0 > k_) ? Q0 : k_;                                             \
        }                                                                         \
    } while (0)

template<int JC>
__global__ __launch_bounds__(256, 2)
void knn_topk(const bf16_t* __restrict__ xp, const float* __restrict__ sqh,
              uint32_t* __restrict__ pkey, uint16_t* __restrict__ pidx)
{
    __shared__ uint32_t lv[4][64][2][LCAP];   // [wave][lane][i-set][slot], 8 KB

    const int m     = blockIdx.z;
    const int chunk = blockIdx.y;
    const int ib    = blockIdx.x * 128;
    const int wave  = threadIdx.x >> 6;
    const int lane  = threadIdx.x & 63;
    const int li    = lane & 15;
    const int g     = lane >> 4;

    const bf16_t* XP = xp + (size_t)m * NP * DIM;
    const float*  SQ = sqh + m * NP;

    const int ti0 = (ib >> 4) + wave * 2;   // first of this wave's two i-tiles

    // B fragments for both i-sets: lane holds B[k=kk*32+g*8+e][col=li] = X[i][k]
    s16x8 bfr0[4], bfr1[4];
    #pragma unroll
    for (int kk = 0; kk < 4; ++kk) {
        bfr0[kk] = *(const s16x8*)(XP + (((size_t)ti0 * 4 + kk) * 64 + (size_t)(g * 16 + li)) * 8);
        bfr1[kk] = *(const s16x8*)(XP + (((size_t)(ti0 + 1) * 4 + kk) * 64 + (size_t)(g * 16 + li)) * 8);
    }

    uint32_t q0 = 0, q1 = 0, q2 = 0, q3 = 0;   // top-4, i-set 0
    uint32_t r0 = 0, r1 = 0, r2 = 0, r3 = 0;   // top-4, i-set 1

    const int TPC = NTILES / JC;           // tiles per chunk (80 at JC=8, even)
    const int t0  = chunk * TPC;

    const bf16_t* XC = XP + (size_t)t0 * 2048;   // chunk base (uniform)
    const float*  SC = SQ + t0 * 16;             // chunk sq base (uniform)
    const int     la = lane * 8;                 // lane A-frag offset (elements, 16B)
    const int     sg = g * 4;                    // lane sq offset

    // Preload tiles 0 (set A) and 1 (set B); sq issued first (oldest -> counted waits).
    f32x4 sA = *(const f32x4*)(SC + sg);
    s16x8 a0 = *(const s16x8*)(XC + la);
    s16x8 a1 = *(const s16x8*)(XC + la + 512);
    s16x8 a2 = *(const s16x8*)(XC + la + 1024);
    s16x8 a3 = *(const s16x8*)(XC + la + 1536);
    f32x4 sB = *(const f32x4*)(SC + sg + 16);
    s16x8 c0 = *(const s16x8*)(XC + la + 2048);
    s16x8 c1 = *(const s16x8*)(XC + la + 2048 + 512);
    s16x8 c2 = *(const s16x8*)(XC + la + 2048 + 1024);
    s16x8 c3 = *(const s16x8*)(XC + la + 2048 + 1536);

    const bf16_t* pfA = XC + 2 * 2048;   // uniform prefetch base, set A (tile 2p+2)
    const bf16_t* pfB = XC + 3 * 2048;   // set B (tile 2p+3)
    const float*  sfA = SC + 2 * 16;
    const float*  sfB = SC + 3 * 16;

    for (int p = 0; p < TPC / 2; ++p) {
        // ---- slot A: compute tile 2p (both i-sets), reload set A with tile 2p+2
        {
            f32x4 acc0 = __builtin_amdgcn_mfma_f32_16x16x32_bf16(a0, bfr0[0], sA, 0, 0, 0);
            f32x4 acc1 = __builtin_amdgcn_mfma_f32_16x16x32_bf16(a0, bfr1[0], sA, 0, 0, 0);
            acc0 = __builtin_amdgcn_mfma_f32_16x16x32_bf16(a1, bfr0[1], acc0, 0, 0, 0);
            acc1 = __builtin_amdgcn_mfma_f32_16x16x32_bf16(a1, bfr1[1], acc1, 0, 0, 0);
            acc0 = __builtin_amdgcn_mfma_f32_16x16x32_bf16(a2, bfr0[2], acc0, 0, 0, 0);
            acc1 = __builtin_amdgcn_mfma_f32_16x16x32_bf16(a2, bfr1[2], acc1, 0, 0, 0);
            acc0 = __builtin_amdgcn_mfma_f32_16x16x32_bf16(a3, bfr0[3], acc0, 0, 0, 0);
            acc1 = __builtin_amdgcn_mfma_f32_16x16x32_bf16(a3, bfr1[3], acc1, 0, 0, 0);
            sA = *(const f32x4*)(sfA + sg);          sfA += 32;
            a0 = *(const s16x8*)(pfA + la);
            a1 = *(const s16x8*)(pfA + la + 512);
            a2 = *(const s16x8*)(pfA + la + 1024);
            a3 = *(const s16x8*)(pfA + la + 1536);   pfA += 4096;
            const uint32_t ib4 = (uint32_t)(p << 3);
            INSERT4(acc0, ib4, q0, q1, q2, q3);
            INSERT4(acc1, ib4, r0, r1, r2, r3);
        }
        // ---- slot B: compute tile 2p+1 (both i-sets), reload set B with tile 2p+3
        {
            f32x4 acc0 = __builtin_amdgcn_mfma_f32_16x16x32_bf16(c0, bfr0[0], sB, 0, 0, 0);
            f32x4 acc1 = __builtin_amdgcn_mfma_f32_16x16x32_bf16(c0, bfr1[0], sB, 0, 0, 0);
            acc0 = __builtin_amdgcn_mfma_f32_16x16x32_bf16(c1, bfr0[1], acc0, 0, 0, 0);
            acc1 = __builtin_amdgcn_mfma_f32_16x16x32_bf16(c1, bfr1[1], acc1, 0, 0, 0);
            acc0 = __builtin_amdgcn_mfma_f32_16x16x32_bf16(c2, bfr0[2], acc0, 0, 0, 0);
            acc1 = __builtin_amdgcn_mfma_f32_16x16x32_bf16(c2, bfr1[2], acc1, 0, 0, 0);
            acc0 = __builtin_amdgcn_mfma_f32_16x16x32_bf16(c3, bfr0[3], acc0, 0, 0, 0);
            acc1 = __builtin_amdgcn_mfma_f32_16x16x32_bf16(c3, bfr1[3], acc1, 0, 0, 0);
            sB = *(const f32x4*)(sfB + sg);          sfB += 32;
            c0 = *(const s16x8*)(pfB + la);
            c1 = *(const s16x8*)(pfB + la + 512);
            c2 = *(const s16x8*)(pfB + la + 1024);
            c3 = *(const s16x8*)(pfB + la + 1536);   pfB += 4096;
            const uint32_t ib4 = (uint32_t)(p << 3) | 4u;
            INSERT4(acc0, ib4, q0, q1, q2, q3);
            INSERT4(acc1, ib4, r0, r1, r2, r3);
        }
    }

    lv[wave][lane][0][0] = q0;  lv[wave][lane][0][1] = q1;
    lv[wave][lane][0][2] = q2;  lv[wave][lane][0][3] = q3;
    lv[wave][lane][1][0] = r0;  lv[wave][lane][1][1] = r1;
    lv[wave][lane][1][2] = r2;  lv[wave][lane][1][3] = r3;
    __syncthreads();

    // 4-way merge of the 4 lane-group top-4 lists; lanes g<2 each handle i-set s=g.
    // TRANSPOSED output: slot-major over i (coalesced here and in merge_count).
    if (g < 2) {
        const int s = g;
        const int i = ib + wave * 32 + s * 16 + li;
        if (i < NROW) {
            int p0 = 0, p1 = 0, p2 = 0, p3 = 0;
            uint32_t v0 = lv[wave][li][s][0];
            uint32_t v1 = lv[wave][16 + li][s][0];
            uint32_t v2 = lv[wave][32 + li][s][0];
            uint32_t v3 = lv[wave][48 + li][s][0];
            uint32_t* ov = pkey + ((size_t)(m * JC + chunk) * KSEL) * NROW + i;
            uint16_t* oi = pidx + ((size_t)(m * JC + chunk) * KSEL) * NROW + i;
            #pragma unroll
            for (int t = 0; t < KSEL; ++t) {
                uint32_t bv = v0; int bg = 0;
                if (v1 > bv) { bv = v1; bg = 1; }
                if (v2 > bv) { bv = v2; bg = 2; }
                if (v3 > bv) { bv = v3; bg = 3; }
                const uint32_t id = bv & 1023u;
                const int j = (t0 + (int)(id >> 2)) * 16 + bg * 4 + (int)(id & 3u);
                if      (bg == 0) { p0++; v0 = p0 < LCAP ? lv[wave][li][s][p0]      : 0u; }
                else if (bg == 1) { p1++; v1 = p1 < LCAP ? lv[wave][16 + li][s][p1] : 0u; }
                else if (bg == 2) { p2++; v2 = p2 < LCAP ? lv[wave][32 + li][s][p2] : 0u; }
                else              { p3++; v3 = p3 < LCAP ? lv[wave][48 + li][s][p3] : 0u; }
                ov[(size_t)t * NROW] = bv; oi[(size_t)t * NROW] = (uint16_t)j;
            }
        }
    }
}

// ---------------------------------------------------------------- merge + count
// One thread per (row, matrix): 8-way merge of the 8 chunk top-15 lists
// (transposed layout -> coalesced), 15 dependent picks; ids land in LDS;
// even threads count the 15x15 intersection with their odd partner.
template<int JC>
__global__ __launch_bounds__(256)
void knn_merge_count(const uint32_t* __restrict__ pkey, const uint16_t* __restrict__ pidx,
                     unsigned* __restrict__ counter)
{
    __shared__ uint16_t ids[256][KSEL + 3];   // 36B row stride -> bank-shifted
    __shared__ int wsum[4];
    const int tid  = blockIdx.x * 256 + threadIdx.x;
    const int m    = tid & 1;
    const int i    = tid >> 1;
    const int lane = threadIdx.x & 63;
    const int wave = threadIdx.x >> 6;

    if (i < NROW) {
        const uint32_t* pv = pkey + (size_t)m * JC * KSEL * NROW + i;
        const uint16_t* px = pidx + (size_t)m * JC * KSEL * NROW + i;
        uint32_t v[JC]; int p[JC];
        #pragma unroll
        for (int c = 0; c < JC; ++c) {
            p[c] = 0;
            v[c] = pv[(size_t)(c * KSEL) * NROW];
        }
        #pragma unroll
        for (int t = 0; t < KSEL; ++t) {
            uint32_t bv = v[0]; int bg = 0;
            #pragma unroll
            for (int c = 1; c < JC; ++c) if (v[c] > bv) { bv = v[c]; bg = c; }
            #pragma unroll
            for (int c = 0; c < JC; ++c)
                if (c == bg) {
                    ids[threadIdx.x][t] = px[(size_t)(c * KSEL + p[c]) * NROW];
                    p[c]++;
                    v[c] = p[c] < KSEL ? pv[(size_t)(c * KSEL + p[c]) * NROW] : 0u;
                }
        }
    }
    __syncthreads();

    int cnt = 0;
    if (i < NROW && m == 0) {
        #pragma unroll
        for (int a = 0; a < KSEL; ++a) {
            const uint16_t x = ids[threadIdx.x][a];
            #pragma unroll
            for (int b = 0; b < KSEL; ++b)
                cnt += (x == ids[threadIdx.x + 1][b]) ? 1 : 0;
        }
    }
    #pragma unroll
    for (int off = 32; off; off >>= 1) cnt += __shfl_down(cnt, off);
    if (lane == 0) wsum[wave] = cnt;
    __syncthreads();
    if (threadIdx.x == 0)
        atomicAdd(counter, (unsigned)(wsum[0] + wsum[1] + wsum[2] + wsum[3]));
}

__global__ void knn_finalize(const unsigned* __restrict__ counter, float* __restrict__ out)
{
    out[0] = 1.0f - (float)(*counter) / (float)(NROW * KSEL);
}

// ---------------------------------------------------------------- launch
#define XPAD (4 * 2048)   // prefetch overrun pad (elements)
#define SQPAD 128         // sq prefetch overrun pad (floats)

static size_t ws_need(int jc)
{
    size_t o = ((size_t)2 * NP * DIM + XPAD) * sizeof(bf16_t)
             + ((size_t)2 * NP + SQPAD) * sizeof(float);
    o = (o + 255) & ~(size_t)255;
    o += (size_t)2 * jc * NROW * KSEL * sizeof(uint32_t);
    o += (size_t)2 * jc * NROW * KSEL * sizeof(uint16_t);
    o = (o + 255) & ~(size_t)255;
    o += 256;
    return o;
}

extern "C" void kernel_launch(void* const* d_in, const int* in_sizes, int n_in,
                              void* d_out, int out_size, void* d_ws, size_t ws_size,
                              hipStream_t stream)
{
    (void)in_sizes; (void)n_in; (void)out_size;
    const float* x0 = (const float*)d_in[0];
    const float* x1 = (const float*)d_in[1];
    float* out = (float*)d_out;

    const int jc = (ws_size >= ws_need(8)) ? 8 : 4;

    char* ws = (char*)d_ws;
    size_t off = 0;
    bf16_t* xp  = (bf16_t*)(ws + off); off += ((size_t)2 * NP * DIM + XPAD) * sizeof(bf16_t);
    float*  sqh = (float*)(ws + off);  off += ((size_t)2 * NP + SQPAD) * sizeof(float);
    off = (off + 255) & ~(size_t)255;
    uint32_t* pkey = (uint32_t*)(ws + off); off += (size_t)2 * jc * NROW * KSEL * sizeof(uint32_t);
    uint16_t* pidx = (uint16_t*)(ws + off); off += (size_t)2 * jc * NROW * KSEL * sizeof(uint16_t);
    off = (off + 255) & ~(size_t)255;
    unsigned* counter = (unsigned*)(ws + off);

    knn_convert<<<(2 * NP) / 4, 256, 0, stream>>>(x0, x1, xp, sqh, counter);
    if (jc == 8) {
        knn_topk<8><<<dim3(NP / 128, 8, 2), 256, 0, stream>>>(xp, sqh, pkey, pidx);
        knn_merge_count<8><<<(2 * NROW + 255) / 256, 256, 0, stream>>>(pkey, pidx, counter);
    } else {
        knn_topk<4><<<dim3(NP / 128, 4, 2), 256, 0, stream>>>(xp, sqh, pkey, pidx);
        knn_merge_count<4><<<(2 * NROW + 255) / 256, 256, 0, stream>>>(pkey, pidx, counter);
    }
    knn_finalize<<<1, 1, 0, stream>>>(counter, out);
}